// Round 10
// baseline (73.996 us; speedup 1.0000x reference)
//
#include <hip/hip_runtime.h>

#define T      64
#define S      32
#define NGRAPH 64
#define NSPLIT 16     // slices per graph -> 1024 blocks of 256 (4 blocks/CU)
#define NW     4
#define MAXC   20     // nodes per staged batch: 60 contiguous floats in SGPRs

// R16: x via wave-uniform SGPR staging, branch-free inner loop.
// R15 post-mortem: staging x through LDS added 3 uniform ds_reads/node
// (9 DS ops/node total) on the shared per-CU LDS pipe AND put ~100cyc of
// ds_read latency at the head of each iteration's dependent chain ->
// partial only 16.4 -> 14.2 us. Fix: per-wave CONTIGUOUS node chunks so
// each wave's ~16-18 nodes (48-60 floats) load once via s_load_dwordx16
// from a uniform address into SGPRs (one overlapped HBM round trip, zero
// DS ops, fma reads the s-operand for free). Inner loop fully unrolled and
// branch-free: invalid iterations fold to ss=64 -> all 3 slots select row
// 0 (trash aliased onto row 0, which v0acc overwrites after the loop) ->
// bins shrinks to exactly 32 KB and the compiler can schedule node k+1's
// VALU above node k's bins RMW. Remaining in-loop DS: the irreducible
// 3 read + 3 write bins RMW (6 ops/node).
//
// bins TRANSPOSED: bins[c*256 + tid] -> bank = tid mod 32, independent of
// the data-dependent slot c; conflict-free by construction.
// Numerics (R9/R10-validated, absmax 4.0): per (node,theta) profile is
// 0..0, sm, s0, ~1..1; 3 deltas at slots ss-1, ss, ss+1 (third ~ 1-s0v,
// err <= 8.2e-4); slots <= 0 fold into base register; slots >= 32 -> row 0
// (dontcare, overwritten). Per-node values identical to R0's validated
// encoding; only wave->node assignment (summation order) changed.
__global__ __launch_bounds__(256, 4) void ect_partial(
    const float* __restrict__ x, const float* __restrict__ v,
    const float* __restrict__ lin, const int* __restrict__ batch,
    float* __restrict__ ws, int n_points)
{
    __shared__ float bins[32 * 256]; // [c][tid]: row 0 base(+trash), 1..31 deltas

    const int tid  = threadIdx.x;
    const int t    = tid & 63;       // lane == theta
    const int w    = __builtin_amdgcn_readfirstlane(tid >> 6); // wave id, SGPR
    const int b    = blockIdx.x;
    const int g    = b >> 4;         // graph
    const int c    = b & (NSPLIT - 1);

    {   // vectorized zero-init of rows 0..31: exactly 8 float4 per thread
        const float4 z4 = {0.0f, 0.0f, 0.0f, 0.0f};
        float4* b4 = (float4*)bins;
#pragma unroll
        for (int i = 0; i < 8; i++) b4[tid + i * 256] = z4;
    }

    // 32-ary ballot search (lanes<32: lower_bound(g), >=32: lower_bound(g+1))
    const int target = (t < 32) ? g : (g + 1);
    const int i32    = t & 31;
    int lo = 0;
    const int strides[3] = {2048, 64, 2};
#pragma unroll
    for (int rnd = 0; rnd < 3; rnd++) {
        const int stride = strides[rnd];
        const int idx  = lo + i32 * stride;
        const int pv   = batch[min(idx, n_points - 1)];
        const bool prd = (idx < n_points) && (pv < target);
        const unsigned long long bal = __ballot(prd);
        const int cnt = __popc((unsigned)(bal >> (t & 32)));
        lo += max(cnt - 1, 0) * stride;
    }
    if ((lo < n_points) && (batch[min(lo, n_points - 1)] < target)) lo++;
    const int gstart = __builtin_amdgcn_readfirstlane(lo);
    const int gend   = __builtin_amdgcn_readlane(lo, 32);
    const int len    = gend - gstart;
    const int n0     = gstart + (len * c) / NSPLIT;
    const int n1     = gstart + (len * (c + 1)) / NSPLIT;

    // per-wave CONTIGUOUS chunk of the slice
    const int len_s = n1 - n0;
    int       nw0   = n0 + (len_s * w) / NW;
    const int nw1   = n0 + (len_s * (w + 1)) / NW;

    const float lin0     = lin[0];
    const float step     = lin[1] - lin0;
    const float inv_step = 1.0f / step;
    const float nl0i     = -lin0 * inv_step;
    const float K2 = (100.0f * step) * 1.4426950408889634f;   // ~10.24
    const float r  = __builtin_amdgcn_exp2f(-K2);

    const float v0 = v[0 * T + t];
    const float v1 = v[1 * T + t];
    const float v2 = v[2 * T + t];

    float v0acc = 0.0f;                 // profile value at s=0
    __syncthreads();                    // zero-init complete

    const int xlim = 3 * n_points;

    while (nw0 < nw1) {                 // normally exactly 1 batch (chunk<=18)
        const int cnt = min(nw1 - nw0, MAXC);
        const int b3  = 3 * nw0;        // wave-uniform -> scalar loads
        float xs[3 * MAXC];
        if (b3 + 3 * MAXC <= xlim) {    // contiguous fast path
#pragma unroll
            for (int i = 0; i < 3 * MAXC; i++) xs[i] = x[b3 + i];
        } else {                        // end-of-buffer: per-element clamp
#pragma unroll
            for (int i = 0; i < 3 * MAXC; i++) xs[i] = x[min(b3 + i, xlim - 1)];
        }
#pragma unroll
        for (int k = 0; k < MAXC; k++) {
            const float x0 = xs[3 * k + 0];
            const float x1 = xs[3 * k + 1];
            const float x2 = xs[3 * k + 2];
            const float nh = fmaf(x0, v0, fmaf(x1, v1, x2 * v2));
            const float f  = fmaf(nh, inv_step, nl0i);
            const float fs = ceilf(f);
            const int   sr = (int)fs;
            const int   ss = (k < cnt) ? sr : 64;   // invalid -> all rows 0
            const float e0 = __builtin_amdgcn_exp2f(fmaf(K2, f - fs, K2)); // (1,e^d]
            const float e1 = e0 * r;                                       // (r,1]
            const float sm  = __builtin_amdgcn_rcpf(1.0f + e0);
            const float s0v = __builtin_amdgcn_rcpf(1.0f + e1);
            v0acc += (ss <= -1) ? 1.0f : (ss == 0 ? s0v : (ss == 1 ? sm : 0.0f));
            // deltas at slots ss-1, ss, ss+1; out-of-range [1,31] -> row 0
            const int p0 = ss - 1, p1 = ss, p2 = ss + 1;
            const int a0 = (((unsigned)(p0 - 1) < 31u) ? p0 : 0) * 256 + tid;
            const int a1 = (((unsigned)(p1 - 1) < 31u) ? p1 : 0) * 256 + tid;
            const int a2 = (((unsigned)(p2 - 1) < 31u) ? p2 : 0) * 256 + tid;
            // reads first, then writes (in-range addrs distinct; row-0 trash
            // dontcare); bank = tid mod 32 for all -> conflict-free
            const float r0 = bins[a0], r1 = bins[a1], r2 = bins[a2];
            bins[a0] = r0 + sm;
            bins[a1] = r1 + (s0v - sm);
            bins[a2] = r2 + (1.0f - s0v);
        }
        nw0 += MAXC;
    }

    bins[tid] = v0acc;                  // row 0: overwrites in-loop trash
    __syncthreads();

    // merge 4 wave-lanes into tid = t (c = 0..31)
    for (int cell = tid; cell < 32 * 64; cell += 256) {
        const int cc = cell >> 6;               // 0..31
        const int tt = cell & 63;
        const float sum = bins[cc * 256 +   0 + tt] + bins[cc * 256 +  64 + tt]
                        + bins[cc * 256 + 128 + tt] + bins[cc * 256 + 192 + tt];
        bins[cc * 256 + tt] = sum;              // same-thread RMW, safe
    }
    __syncthreads();

    // prefix over c and coalesced store: wave w covers s in [8w, 8w+8)
    float run = bins[0 * 256 + t];              // base = value at s=0
    const int sbase = 8 * w;
    for (int cc = 1; cc < sbase; cc++) run += bins[cc * 256 + t];
    float* wsb = ws + (size_t)b * (S * T);
#pragma unroll
    for (int j = 0; j < 8; j++) {
        const int s = sbase + j;
        if (s >= 1) run += bins[s * 256 + t];
        wsb[s * T + t] = run;
    }
}

// Phase 2: out[g][i] = sum of 16 slice partials, float2-wide.
// float2 (not float4) so 256 blocks cover all 256 CUs (float4 gave 128
// blocks = half the chip idle). Plain stores cover the whole output.
__global__ __launch_bounds__(256) void ect_reduce(
    const float2* __restrict__ ws2, float2* __restrict__ out2)
{
    const int idx = blockIdx.x * 256 + threadIdx.x;  // [0, 64*1024)
    const int g   = idx >> 10;                       // 1024 float2 per graph
    const int i   = idx & 1023;
    float2 sum = {0.0f, 0.0f};
#pragma unroll
    for (int c = 0; c < NSPLIT; c++) {
        const float2 a = ws2[(size_t)(g * NSPLIT + c) * 1024 + i];
        sum.x += a.x; sum.y += a.y;
    }
    out2[idx] = sum;
}

extern "C" void kernel_launch(void* const* d_in, const int* in_sizes, int n_in,
                              void* d_out, int out_size, void* d_ws, size_t ws_size,
                              hipStream_t stream) {
    const float* x     = (const float*)d_in[0];
    const float* v     = (const float*)d_in[1];
    const float* lin   = (const float*)d_in[2];
    const int*   batch = (const int*)d_in[3];
    float* out = (float*)d_out;
    float* ws  = (float*)d_ws;                   // 1024 * 2048 floats = 8.4 MB

    const int n_points = in_sizes[0] / 3;

    ect_partial<<<NGRAPH * NSPLIT, 256, 0, stream>>>(x, v, lin, batch, ws, n_points);
    ect_reduce<<<NGRAPH * S * T / 2 / 256, 256, 0, stream>>>(
        (const float2*)ws, (float2*)out);
}

// Round 11
// 71.928 us; speedup vs baseline: 1.0288x; 1.0288x over previous
//
#include <hip/hip_runtime.h>

#define T      64
#define S      32
#define NGRAPH 64
#define NSPLIT 16     // slices per graph -> 1024 blocks of 256 (4 blocks/CU)
#define NW     4
#define XCAP   128    // staged-node capacity (x4: 128 nodes * 16B = 2 KB)

// R17: cut LDS ops + fuse output. R15 anchor (71.68us, partial ~14.2) was
// LDS-pipe bound: 9 DS ops/node (3 x-reads + 3+3 bins RMW) + epilogue ~=
// 8.2us floor. Changes:
//  (1) x_lds padded [n][4] -> single uniform ds_read_b128 per node (3->1).
//  (2) bins split into 2 half-arrays [32][128], wave-pair -> own half,
//      col=(w&1)*64+t. Stride 128 dwords: bank = col mod 32 (conflict-free,
//      slot-independent, same guarantee as the 256-stride layout) AND the
//      3 slot rows are 128 dwords apart -> ds_read2_b32/ds_write2_b32
//      merge (offset1:128 <= 255), 6 RMW ops -> ~4.
//      Slot triple rebased to contiguous rows pb,pb+1,pb+2, pb =
//      med3(ss-1,0,29), with per-row amount select -- verified identical
//      to the R9/R10-validated delta encoding for every ss (row 0 = trash,
//      overwritten by v0acc; clamped cases add 0.0 to untouched rows).
//  (3) ect_reduce dropped: blocks atomicAdd prefixed rows into out
//      (native global_atomic_add_f32, no-return; NOT the LDS-float CAS
//      trap of R13). hipMemsetAsync zeroes out first. Removes a kernel
//      launch + gap and the 8.4 MB ws round-trip; ws now unused.
// Numerics: per-node amounts unchanged (sm, s0v-sm, 1-s0v at rows ss-1,
// ss, ss+1; base in v0acc); only summation order across slices changes
// (atomic order), ~1-ulp class.
__global__ __launch_bounds__(256, 4) void ect_partial(
    const float* __restrict__ x, const float* __restrict__ v,
    const float* __restrict__ lin, const int* __restrict__ batch,
    float* __restrict__ out, int n_points)
{
    __shared__ float bins[2][32][128]; // [half][row][col]; row 0 base+trash
    __shared__ float x4[XCAP * 4];     // staged x, padded to 16B/node

    const int tid  = threadIdx.x;
    const int t    = tid & 63;       // lane == theta
    const int w    = __builtin_amdgcn_readfirstlane(tid >> 6); // wave id, SGPR
    const int half = w >> 1;
    const int col  = ((w & 1) << 6) + t;
    float* bw = &bins[half][0][0];   // this wave's half-array
    const int b    = blockIdx.x;
    const int g    = b >> 4;         // graph
    const int c    = b & (NSPLIT - 1);

    {   // vectorized zero-init: 8192 dwords = 2048 float4, 8 per thread
        const float4 z4 = {0.0f, 0.0f, 0.0f, 0.0f};
        float4* b4 = (float4*)&bins[0][0][0];
#pragma unroll
        for (int i = 0; i < 8; i++) b4[tid + i * 256] = z4;
    }

    // 32-ary ballot search (lanes<32: lower_bound(g), >=32: lower_bound(g+1))
    const int target = (t < 32) ? g : (g + 1);
    const int i32    = t & 31;
    int lo = 0;
    const int strides[3] = {2048, 64, 2};
#pragma unroll
    for (int rnd = 0; rnd < 3; rnd++) {
        const int stride = strides[rnd];
        const int idx  = lo + i32 * stride;
        const int pv   = batch[min(idx, n_points - 1)];
        const bool prd = (idx < n_points) && (pv < target);
        const unsigned long long bal = __ballot(prd);
        const int cnt = __popc((unsigned)(bal >> (t & 32)));
        lo += max(cnt - 1, 0) * stride;
    }
    if ((lo < n_points) && (batch[min(lo, n_points - 1)] < target)) lo++;
    const int gstart = __builtin_amdgcn_readfirstlane(lo);
    const int gend   = __builtin_amdgcn_readlane(lo, 32);
    const int len    = gend - gstart;
    const int n0     = gstart + (len * c) / NSPLIT;
    const int n1     = gstart + (len * (c + 1)) / NSPLIT;
    const int sliceLen = n1 - n0;

    {   // coalesced staging into padded [n][4] layout (<=2 dwords/thread)
        const int limit = 3 * min(sliceLen, XCAP);
        const int base3 = 3 * n0;
        for (int p = tid; p < limit; p += 256) {
            const int n = p / 3;              // magic-mul, compiler
            const int d = p - 3 * n;
            x4[n * 4 + d] = x[base3 + p];     // base3+p < 3*n1 <= 3*n_points
        }
    }

    const float lin0     = lin[0];
    const float step     = lin[1] - lin0;
    const float inv_step = 1.0f / step;
    const float nl0i     = -lin0 * inv_step;
    const float K2 = (100.0f * step) * 1.4426950408889634f;   // ~10.24
    const float r  = __builtin_amdgcn_exp2f(-K2);

    const float v0 = v[0 * T + t];
    const float v1 = v[1 * T + t];
    const float v2 = v[2 * T + t];

    float v0acc = 0.0f;                 // profile value at s=0
    __syncthreads();                    // init + staging complete

#define ECT_BODY(X0, X1, X2)                                                  \
    {                                                                         \
        const float nh = fmaf((X0), v0, fmaf((X1), v1, (X2) * v2));           \
        const float f  = fmaf(nh, inv_step, nl0i);                            \
        const float fs = ceilf(f);                                            \
        const int   ss = (int)fs;                                             \
        const float e0 = __builtin_amdgcn_exp2f(fmaf(K2, f - fs, K2));        \
        const float e1 = e0 * r;                                              \
        const float sm  = __builtin_amdgcn_rcpf(1.0f + e0);                   \
        const float s0v = __builtin_amdgcn_rcpf(1.0f + e1);                   \
        v0acc += (ss <= -1) ? 1.0f : (ss == 0 ? s0v : (ss == 1 ? sm : 0.0f)); \
        const float d1 = s0v - sm, d2 = 1.0f - s0v;                           \
        const int pb = min(max(ss - 1, 0), 29);        /* v_med3_i32 */       \
        /* rows pb,pb+1,pb+2: amount = sm at ss-1, d1 at ss, d2 at ss+1,   */ \
        /* else 0 (row 0 = dontcare trash, overwritten by v0acc below)     */ \
        const float amt0 = (pb     == ss - 1) ? sm : 0.0f;                    \
        const float amt1 = (pb + 1 == ss    ) ? d1                            \
                         : (pb + 1 == ss + 1) ? d2                            \
                         : (pb + 1 == ss - 1) ? sm : 0.0f;                    \
        const float amt2 = (pb + 2 == ss + 1) ? d2                            \
                         : (pb + 2 == ss    ) ? d1                            \
                         : (pb + 2 == ss - 1) ? sm : 0.0f;                    \
        const int a = pb * 128 + col;                                         \
        const float r0 = bw[a], r1 = bw[a + 128], r2 = bw[a + 256];           \
        bw[a]       = r0 + amt0;                                              \
        bw[a + 128] = r1 + amt1;                                              \
        bw[a + 256] = r2 + amt2;                                              \
    }

    if (sliceLen <= XCAP) {             // staged path (always, in practice)
#pragma unroll 4
        for (int n = w; n < sliceLen; n += NW) {
            const float4 xv = *(const float4*)&x4[n * 4]; // uniform b128
            ECT_BODY(xv.x, xv.y, xv.z)
        }
    } else {                            // safety fallback: direct global
#pragma unroll 2
        for (int n = n0 + w; n < n1; n += NW) {
            const float x0 = x[3 * n + 0];
            const float x1 = x[3 * n + 1];
            const float x2 = x[3 * n + 2];
            ECT_BODY(x0, x1, x2)
        }
    }
#undef ECT_BODY

    bw[col] = v0acc;                    // row 0 of own half: base value
    __syncthreads();

    // merge 4 columns (2 per half) into bins[0][cc][tt]
    for (int cell = tid; cell < 32 * 64; cell += 256) {
        const int cc = cell >> 6;               // 0..31
        const int tt = cell & 63;
        const float sum = bins[0][cc][tt] + bins[0][cc][64 + tt]
                        + bins[1][cc][tt] + bins[1][cc][64 + tt];
        bins[0][cc][tt] = sum;          // read/write same cell same thread
    }
    __syncthreads();

    // prefix over rows and atomic-accumulate into out (reduce kernel fused)
    float run = bins[0][0][t];                  // base = value at s=0
    const int sbase = 8 * w;
    for (int cc = 1; cc < sbase; cc++) run += bins[0][cc][t];
    float* outg = out + (size_t)g * (S * T);
#pragma unroll
    for (int j = 0; j < 8; j++) {
        const int s = sbase + j;
        if (s >= 1) run += bins[0][s][t];
        atomicAdd(&outg[s * T + t], run);       // global_atomic_add_f32
    }
}

extern "C" void kernel_launch(void* const* d_in, const int* in_sizes, int n_in,
                              void* d_out, int out_size, void* d_ws, size_t ws_size,
                              hipStream_t stream) {
    const float* x     = (const float*)d_in[0];
    const float* v     = (const float*)d_in[1];
    const float* lin   = (const float*)d_in[2];
    const int*   batch = (const int*)d_in[3];
    float* out = (float*)d_out;
    (void)d_ws; (void)ws_size;                   // workspace unused now

    const int n_points = in_sizes[0] / 3;

    hipMemsetAsync(d_out, 0, out_size, stream);  // 512 KB, capture-safe
    ect_partial<<<NGRAPH * NSPLIT, 256, 0, stream>>>(x, v, lin, batch, out, n_points);
}